// Round 1
// 479.290 us; speedup vs baseline: 1.0091x; 1.0091x over previous
//
#include <hip/hip_runtime.h>
#include <stdint.h>

typedef __attribute__((ext_vector_type(8))) short short8;
typedef __attribute__((ext_vector_type(4))) float floatx4;
typedef unsigned short u16;
typedef unsigned int u32;

#define MFMA16(a,b,c) __builtin_amdgcn_mfma_f32_16x16x32_bf16((a),(b),(c),0,0,0)

__device__ __forceinline__ u16 f2b(float f){
  u32 i; __builtin_memcpy(&i,&f,4); i += 0x7FFFu + ((i>>16)&1u); return (u16)(i>>16);
}
__device__ __forceinline__ int regid(int p){ return (p<56)?0:((p<60)?1:2); }

// LDS (u16 elems), total 26112 elems = 52224 B -> 3 blocks/CU:
//   XW : xw[64][264] (phase 1-2) -> y[64][264] (phase 3-4)       16896 elems
//   SC : per-wave scratch [64][36] x4 -- q/k/P in 32-col halves,
//        v as [32ch][72tok] halves                                9216 elems
#define SCO 16896
#define LDS_ELEMS 26112

__global__ void prep_w(const float* __restrict__ wqkv, const float* __restrict__ wo,
                       u16* __restrict__ wqkvT, u16* __restrict__ woT){
  int idx = blockIdx.x*256 + threadIdx.x;
  if(idx < 768*256){ int n = idx>>8, k = idx&255; wqkvT[idx] = f2b(wqkv[k*768 + n]); }
  else { int j = idx - 768*256; int n = j>>8, k = j&255; woT[j] = f2b(wo[k*256 + n]); }
}

__global__ __launch_bounds__(256,3) void swmsa_fused(
    const float* __restrict__ x, const u16* __restrict__ wqkvT, const float* __restrict__ bqkv,
    const u16* __restrict__ woT, const float* __restrict__ bo, const float* __restrict__ table,
    float* __restrict__ out)
{
  extern __shared__ u16 lds[];
  const int tid  = threadIdx.x;
  const int wave = tid>>6, lane = tid&63;
  const int quad = lane>>4, colid = lane&15;
  // XCD swizzle: 8 windows of one image-row run consecutively on one XCD
  const int bi = blockIdx.x;
  const int xcd = bi & 7, j = bi >> 3;
  const int r0 = ((j >> 3) << 3) | xcd;   // row id = b*8+wy, 0..255
  const int wx = j & 7;
  const int b = r0 >> 3, wy = r0 & 7;
  const size_t imgbase = (size_t)b*256*4096;
  const int w0 = wx*8+4;
  const floatx4 fzero = {0.f,0.f,0.f,0.f};
  u16* sc = lds + SCO + wave*2304;

  // ---- Phase 1: gather shifted window, f32->bf16, transpose-pack, xw[tok][ch] ----
  for(int i=0;i<2;++i){
    int unit = tid + 256*i;
    int cg = unit>>3, ty = unit&7;
    int hs = (wy*8+ty+4)&63;
    u16 vv[4][8];
    #pragma unroll
    for(int cc=0;cc<4;++cc){
      const float* src = x + imgbase + (size_t)(cg*4+cc)*4096 + (size_t)hs*64;
      floatx4 lo, hi;
      if(wx<7){ lo = *(const floatx4*)(src+w0); hi = *(const floatx4*)(src+w0+4); }
      else    { lo = *(const floatx4*)(src+60); hi = *(const floatx4*)(src); }
      #pragma unroll
      for(int t=0;t<4;++t){ vv[cc][t]=f2b(lo[t]); vv[cc][4+t]=f2b(hi[t]); }
    }
    #pragma unroll
    for(int t=0;t<8;++t){
      uint64_t pk = (uint64_t)vv[0][t] | ((uint64_t)vv[1][t]<<16)
                  | ((uint64_t)vv[2][t]<<32) | ((uint64_t)vv[3][t]<<48);
      *(uint64_t*)&lds[(ty*8+t)*264 + cg*4] = pk;
    }
  }
  __syncthreads();

  // ---- Phase 2: qkv = xw @ w_qkv + b_qkv; frags -> regs via 32-col half round trips ----
  short8 aq2[2][4], bk2[2][4], bv2[2][2][2];
  for(int t3=0; t3<3; ++t3){
    const int cc = 2 - t3;                    // v, k, q (q last: short aq2 lifetime)
    const int col0 = (cc*4 + wave)*64;
    const u16* wslab = wqkvT + (size_t)(col0+colid)*256 + quad*8;
    floatx4 acc[4][4];
    #pragma unroll
    for(int mt=0;mt<4;++mt)
      #pragma unroll
      for(int nt=0;nt<4;++nt) acc[mt][nt] = fzero;
    // software-pipelined B-frag loads (L2-latency hiding within the wave)
    short8 bcur[4], bnxt[4];
    #pragma unroll
    for(int nt=0;nt<4;++nt) bcur[nt] = *(const short8*)&wslab[(size_t)nt*16*256];
    for(int k0=0;k0<256;k0+=32){
      short8 af[4];
      #pragma unroll
      for(int mt=0;mt<4;++mt) af[mt]  = *(const short8*)&lds[(mt*16+colid)*264 + k0 + quad*8];
      if(k0 < 224){
        #pragma unroll
        for(int nt=0;nt<4;++nt) bnxt[nt] = *(const short8*)&wslab[(size_t)nt*16*256 + k0 + 32];
      }
      #pragma unroll
      for(int mt=0;mt<4;++mt)
        #pragma unroll
        for(int nt=0;nt<4;++nt) acc[mt][nt] = MFMA16(af[mt], bcur[nt], acc[mt][nt]);
      #pragma unroll
      for(int nt=0;nt<4;++nt) bcur[nt] = bnxt[nt];
    }
    // epilogue in two 32-col halves through wave-private scratch
    #pragma unroll
    for(int hf=0; hf<2; ++hf){
      #pragma unroll
      for(int nt2=0; nt2<2; ++nt2){
        int nt = hf*2 + nt2;
        float bias = bqkv[col0 + nt*16 + colid];
        #pragma unroll
        for(int mt=0;mt<4;++mt)
          #pragma unroll
          for(int rr=0;rr<4;++rr){
            int row = mt*16 + quad*4 + rr;
            u16 bvv = f2b(acc[mt][nt][rr] + bias);
            if(cc==2) sc[(nt2*16+colid)*72 + row] = bvv;     // vt[ch_local][tok]
            else      sc[row*36 + nt2*16 + colid] = bvv;     // [tok][ch_local]
          }
      }
      if(cc==2){
        #pragma unroll
        for(int n2=0;n2<2;++n2)
          #pragma unroll
          for(int kc=0;kc<2;++kc)
            bv2[hf][n2][kc] = *(const short8*)&sc[(n2*16+colid)*72 + kc*32 + quad*8];
      } else if(cc==1){
        #pragma unroll
        for(int mt=0;mt<4;++mt) bk2[hf][mt] = *(const short8*)&sc[(mt*16+colid)*36 + quad*8];
      } else {
        #pragma unroll
        for(int mt=0;mt<4;++mt) aq2[hf][mt] = *(const short8*)&sc[(mt*16+colid)*36 + quad*8];
      }
    }
  }
  __syncthreads();   // all waves done with xw; XW becomes y

  // ---- Phase 3: attention, 2 heads/wave, barrier-free ----
  const float scale = 0.17677669529663687f;  // 32^-0.5
  #pragma unroll
  for(int hi=0; hi<2; ++hi){
    const int h = wave*2 + hi;
    floatx4 s[4][4];
    #pragma unroll
    for(int mt=0;mt<4;++mt)
      #pragma unroll
      for(int nt=0;nt<4;++nt) s[mt][nt] = MFMA16(aq2[hi][mt], bk2[hi][nt], fzero);
    int cntk[4], kys[4], kxs[4];
    #pragma unroll
    for(int nt=0;nt<4;++nt){
      int col = nt*16 + colid;
      kys[nt] = col>>3; kxs[nt] = col&7;
      cntk[nt] = regid(wy*8 + kys[nt])*3 + regid(wx*8 + kxs[nt]);
    }
    #pragma unroll
    for(int mt=0;mt<4;++mt)
      #pragma unroll
      for(int rr=0;rr<4;++rr){
        int row = mt*16 + quad*4 + rr;
        int ty = row>>3, tx = row&7;
        int cntq = regid(wy*8+ty)*3 + regid(wx*8+tx);
        #pragma unroll
        for(int nt=0;nt<4;++nt){
          int rel = (ty - kys[nt] + 7)*15 + (tx - kxs[nt] + 7);
          float add = table[rel*8 + h] + ((cntq==cntk[nt]) ? 0.f : -100.f);
          s[mt][nt][rr] = s[mt][nt][rr]*scale + add;
        }
      }
    // softmax; write keys 0-31 to scratch, park keys 32-63 packed-bf16 in regs
    u32 gpk[4][4];
    #pragma unroll
    for(int mt=0;mt<4;++mt)
      #pragma unroll
      for(int rr=0;rr<4;++rr){
        float mx = s[mt][0][rr];
        #pragma unroll
        for(int nt=1;nt<4;++nt) mx = fmaxf(mx, s[mt][nt][rr]);
        #pragma unroll
        for(int d=1; d<16; d<<=1) mx = fmaxf(mx, __shfl_xor(mx, d));
        float e[4], sum = 0.f;
        #pragma unroll
        for(int nt=0;nt<4;++nt){ e[nt] = __expf(s[mt][nt][rr]-mx); sum += e[nt]; }
        #pragma unroll
        for(int d=1; d<16; d<<=1) sum += __shfl_xor(sum, d);
        float inv = 1.0f/sum;
        int row = mt*16 + quad*4 + rr;
        sc[row*36 + colid]      = f2b(e[0]*inv);
        sc[row*36 + 16 + colid] = f2b(e[1]*inv);
        gpk[mt][rr] = (u32)f2b(e[2]*inv) | ((u32)f2b(e[3]*inv) << 16);
      }
    floatx4 o[4][2];
    #pragma unroll
    for(int mt=0;mt<4;++mt){ o[mt][0]=fzero; o[mt][1]=fzero; }
    #pragma unroll
    for(int kc=0;kc<2;++kc){
      if(kc==1){
        #pragma unroll
        for(int mt=0;mt<4;++mt)
          #pragma unroll
          for(int rr=0;rr<4;++rr){
            int row = mt*16 + quad*4 + rr;
            sc[row*36 + colid]      = (u16)(gpk[mt][rr] & 0xffffu);
            sc[row*36 + 16 + colid] = (u16)(gpk[mt][rr] >> 16);
          }
      }
      short8 ap[4];
      #pragma unroll
      for(int mt=0;mt<4;++mt) ap[mt] = *(const short8*)&sc[(mt*16+colid)*36 + quad*8];
      #pragma unroll
      for(int mt=0;mt<4;++mt)
        #pragma unroll
        for(int n2=0;n2<2;++n2) o[mt][n2] = MFMA16(ap[mt], bv2[hi][n2][kc], o[mt][n2]);
    }
    // y into XW (wave-own columns)
    #pragma unroll
    for(int n2=0;n2<2;++n2){
      int c = h*32 + n2*16 + colid;
      #pragma unroll
      for(int mt=0;mt<4;++mt)
        #pragma unroll
        for(int rr=0;rr<4;++rr)
          lds[(mt*16+quad*4+rr)*264 + c] = f2b(o[mt][n2][rr]);
    }
  }
  __syncthreads();   // y complete; phase 4 only reads LDS -> barrier-free to the end

  // ---- Phase 4: out = y @ w_o + b_o; all 4 quarters accumulate together,
  //      shared ay frags, direct global store from acc regs (no LDS staging, no barriers).
  //      Lane holds out[tok=16mt+4*quad+rr][ch=np*64+wave*16+colid]:
  //      rr runs over 4 consecutive window columns -> one 16B store.
  {
    floatx4 acc[4][4];   // [np][mt]
    #pragma unroll
    for(int np=0;np<4;++np)
      #pragma unroll
      for(int mt=0;mt<4;++mt) acc[np][mt] = fzero;
    const u16* wbase = woT + (size_t)(wave*16+colid)*256 + quad*8;
    for(int k0=0;k0<256;k0+=32){
      short8 ay[4];
      #pragma unroll
      for(int mt=0;mt<4;++mt) ay[mt] = *(const short8*)&lds[(mt*16+colid)*264 + k0 + quad*8];
      #pragma unroll
      for(int np=0;np<4;++np){
        short8 bw = *(const short8*)&wbase[(size_t)np*16384 + k0];
        #pragma unroll
        for(int mt=0;mt<4;++mt) acc[np][mt] = MFMA16(ay[mt], bw, acc[np][mt]);
      }
    }
    const int ty_base = quad>>1, txg = quad&1;
    const int col = (wx<7) ? (w0 + 4*txg) : (txg ? 0 : 60);
    #pragma unroll
    for(int np=0;np<4;++np){
      const int ch = np*64 + wave*16 + colid;
      const float bias = bo[ch];
      float* chbase = out + imgbase + (size_t)ch*4096;
      #pragma unroll
      for(int mt=0;mt<4;++mt){
        int ty = 2*mt + ty_base;
        int hd = (wy*8 + ty + 4) & 63;
        floatx4 vsto = acc[np][mt];
        vsto[0]+=bias; vsto[1]+=bias; vsto[2]+=bias; vsto[3]+=bias;
        *(floatx4*)(chbase + (size_t)hd*64 + col) = vsto;
      }
    }
  }
}

extern "C" void kernel_launch(void* const* d_in, const int* in_sizes, int n_in,
                              void* d_out, int out_size, void* d_ws, size_t ws_size,
                              hipStream_t stream) {
  const float* x     = (const float*)d_in[0];
  const float* wqkv  = (const float*)d_in[1];
  const float* bqkv  = (const float*)d_in[2];
  const float* wo    = (const float*)d_in[3];
  const float* bo    = (const float*)d_in[4];
  const float* table = (const float*)d_in[5];
  float* out = (float*)d_out;

  u16* wqkvT = (u16*)d_ws;            // 768x256 bf16
  u16* woT   = wqkvT + 768*256;       // 256x256 bf16

  prep_w<<<1024, 256, 0, stream>>>(wqkv, wo, wqkvT, woT);

  (void)hipFuncSetAttribute((const void*)swmsa_fused,
                            hipFuncAttributeMaxDynamicSharedMemorySize, LDS_ELEMS*2);
  swmsa_fused<<<2048, 256, LDS_ELEMS*2, stream>>>(x, wqkvT, bqkv, woT, bo, table, out);
}

// Round 3
// 473.566 us; speedup vs baseline: 1.0213x; 1.0121x over previous
//
#include <hip/hip_runtime.h>
#include <stdint.h>

typedef __attribute__((ext_vector_type(8))) short short8;
typedef __attribute__((ext_vector_type(4))) float floatx4;
typedef unsigned short u16;
typedef unsigned int u32;

#define MFMA16(a,b,c) __builtin_amdgcn_mfma_f32_16x16x32_bf16((a),(b),(c),0,0,0)

__device__ __forceinline__ u16 f2b(float f){
  u32 i; __builtin_memcpy(&i,&f,4); i += 0x7FFFu + ((i>>16)&1u); return (u16)(i>>16);
}
__device__ __forceinline__ int regid(int p){ return (p<56)?0:((p<60)?1:2); }

// LDS (u16 elems) for attention kernel, total 26112 elems = 52224 B -> 3 blocks/CU:
//   XW : xw[64][264] (phase 1-2) -> y[64][264] (phase 3)          16896 elems
//   SC : per-wave scratch [64][36] x4                              9216 elems
#define SCO 16896
#define LDS_ELEMS 26112

__global__ void prep_w(const float* __restrict__ wqkv, const float* __restrict__ wo,
                       u16* __restrict__ wqkvT, u16* __restrict__ woT){
  int idx = blockIdx.x*256 + threadIdx.x;
  if(idx < 768*256){ int n = idx>>8, k = idx&255; wqkvT[idx] = f2b(wqkv[k*768 + n]); }
  else { int j = idx - 768*256; int n = j>>8, k = j&255; woT[j] = f2b(wo[k*256 + n]); }
}

// ================= Kernel A: phases 1-3, dump y to workspace =================
// y layout: [band = b*8+wy][t = tyw*64 + img_col][ch 256] bf16 (rows 512B, coalesced)
__global__ __launch_bounds__(256,3) void swmsa_attn(
    const float* __restrict__ x, const u16* __restrict__ wqkvT, const float* __restrict__ bqkv,
    const float* __restrict__ table, u16* __restrict__ yws)
{
  extern __shared__ u16 lds[];
  const int tid  = threadIdx.x;
  const int wave = tid>>6, lane = tid&63;
  const int quad = lane>>4, colid = lane&15;
  // XCD swizzle: 8 windows of one image-row band run consecutively on one XCD
  const int bi = blockIdx.x;
  const int xcd = bi & 7, j = bi >> 3;
  const int r0 = ((j >> 3) << 3) | xcd;   // band id = b*8+wy, 0..255
  const int wx = j & 7;
  const int b = r0 >> 3, wy = r0 & 7;
  const size_t imgbase = (size_t)b*256*4096;
  const int w0 = wx*8+4;
  const floatx4 fzero = {0.f,0.f,0.f,0.f};
  u16* sc = lds + SCO + wave*2304;

  // ---- Phase 1: gather shifted window, f32->bf16, transpose-pack, xw[tok][ch] ----
  for(int i=0;i<2;++i){
    int unit = tid + 256*i;
    int cg = unit>>3, ty = unit&7;
    int hs = (wy*8+ty+4)&63;
    u16 vv[4][8];
    #pragma unroll
    for(int cc=0;cc<4;++cc){
      const float* src = x + imgbase + (size_t)(cg*4+cc)*4096 + (size_t)hs*64;
      floatx4 lo, hi;
      if(wx<7){ lo = *(const floatx4*)(src+w0); hi = *(const floatx4*)(src+w0+4); }
      else    { lo = *(const floatx4*)(src+60); hi = *(const floatx4*)(src); }
      #pragma unroll
      for(int t=0;t<4;++t){ vv[cc][t]=f2b(lo[t]); vv[cc][4+t]=f2b(hi[t]); }
    }
    #pragma unroll
    for(int t=0;t<8;++t){
      uint64_t pk = (uint64_t)vv[0][t] | ((uint64_t)vv[1][t]<<16)
                  | ((uint64_t)vv[2][t]<<32) | ((uint64_t)vv[3][t]<<48);
      *(uint64_t*)&lds[(ty*8+t)*264 + cg*4] = pk;
    }
  }
  __syncthreads();

  // ---- Phase 2: qkv = xw @ w_qkv + b_qkv ----
  short8 aq2[2][4], bk2[2][4], bv2[2][2][2];
  for(int t3=0; t3<3; ++t3){
    const int cc = 2 - t3;                    // v, k, q
    const int col0 = (cc*4 + wave)*64;
    const u16* wslab = wqkvT + (size_t)(col0+colid)*256 + quad*8;
    floatx4 acc[4][4];
    #pragma unroll
    for(int mt=0;mt<4;++mt)
      #pragma unroll
      for(int nt=0;nt<4;++nt) acc[mt][nt] = fzero;
    short8 bcur[4], bnxt[4];
    #pragma unroll
    for(int nt=0;nt<4;++nt) bcur[nt] = *(const short8*)&wslab[(size_t)nt*16*256];
    for(int k0=0;k0<256;k0+=32){
      short8 af[4];
      #pragma unroll
      for(int mt=0;mt<4;++mt) af[mt]  = *(const short8*)&lds[(mt*16+colid)*264 + k0 + quad*8];
      if(k0 < 224){
        #pragma unroll
        for(int nt=0;nt<4;++nt) bnxt[nt] = *(const short8*)&wslab[(size_t)nt*16*256 + k0 + 32];
      }
      #pragma unroll
      for(int mt=0;mt<4;++mt)
        #pragma unroll
        for(int nt=0;nt<4;++nt) acc[mt][nt] = MFMA16(af[mt], bcur[nt], acc[mt][nt]);
      #pragma unroll
      for(int nt=0;nt<4;++nt) bcur[nt] = bnxt[nt];
    }
    #pragma unroll
    for(int hf=0; hf<2; ++hf){
      #pragma unroll
      for(int nt2=0; nt2<2; ++nt2){
        int nt = hf*2 + nt2;
        float bias = bqkv[col0 + nt*16 + colid];
        #pragma unroll
        for(int mt=0;mt<4;++mt)
          #pragma unroll
          for(int rr=0;rr<4;++rr){
            int row = mt*16 + quad*4 + rr;
            u16 bvv = f2b(acc[mt][nt][rr] + bias);
            if(cc==2) sc[(nt2*16+colid)*72 + row] = bvv;     // vt[ch_local][tok]
            else      sc[row*36 + nt2*16 + colid] = bvv;     // [tok][ch_local]
          }
      }
      if(cc==2){
        #pragma unroll
        for(int n2=0;n2<2;++n2)
          #pragma unroll
          for(int kc=0;kc<2;++kc)
            bv2[hf][n2][kc] = *(const short8*)&sc[(n2*16+colid)*72 + kc*32 + quad*8];
      } else if(cc==1){
        #pragma unroll
        for(int mt=0;mt<4;++mt) bk2[hf][mt] = *(const short8*)&sc[(mt*16+colid)*36 + quad*8];
      } else {
        #pragma unroll
        for(int mt=0;mt<4;++mt) aq2[hf][mt] = *(const short8*)&sc[(mt*16+colid)*36 + quad*8];
      }
    }
  }
  __syncthreads();   // all waves done with xw; XW becomes y

  // ---- Phase 3: attention, 2 heads/wave, barrier-free ----
  const float scale = 0.17677669529663687f;  // 32^-0.5
  #pragma unroll
  for(int hi=0; hi<2; ++hi){
    const int h = wave*2 + hi;
    floatx4 s[4][4];
    #pragma unroll
    for(int mt=0;mt<4;++mt)
      #pragma unroll
      for(int nt=0;nt<4;++nt) s[mt][nt] = MFMA16(aq2[hi][mt], bk2[hi][nt], fzero);
    int cntk[4], kys[4], kxs[4];
    #pragma unroll
    for(int nt=0;nt<4;++nt){
      int col = nt*16 + colid;
      kys[nt] = col>>3; kxs[nt] = col&7;
      cntk[nt] = regid(wy*8 + kys[nt])*3 + regid(wx*8 + kxs[nt]);
    }
    #pragma unroll
    for(int mt=0;mt<4;++mt)
      #pragma unroll
      for(int rr=0;rr<4;++rr){
        int row = mt*16 + quad*4 + rr;
        int ty = row>>3, tx = row&7;
        int cntq = regid(wy*8+ty)*3 + regid(wx*8+tx);
        #pragma unroll
        for(int nt=0;nt<4;++nt){
          int rel = (ty - kys[nt] + 7)*15 + (tx - kxs[nt] + 7);
          float add = table[rel*8 + h] + ((cntq==cntk[nt]) ? 0.f : -100.f);
          s[mt][nt][rr] = s[mt][nt][rr]*scale + add;
        }
      }
    u32 gpk[4][4];
    #pragma unroll
    for(int mt=0;mt<4;++mt)
      #pragma unroll
      for(int rr=0;rr<4;++rr){
        float mx = s[mt][0][rr];
        #pragma unroll
        for(int nt=1;nt<4;++nt) mx = fmaxf(mx, s[mt][nt][rr]);
        #pragma unroll
        for(int d=1; d<16; d<<=1) mx = fmaxf(mx, __shfl_xor(mx, d));
        float e[4], sum = 0.f;
        #pragma unroll
        for(int nt=0;nt<4;++nt){ e[nt] = __expf(s[mt][nt][rr]-mx); sum += e[nt]; }
        #pragma unroll
        for(int d=1; d<16; d<<=1) sum += __shfl_xor(sum, d);
        float inv = 1.0f/sum;
        int row = mt*16 + quad*4 + rr;
        sc[row*36 + colid]      = f2b(e[0]*inv);
        sc[row*36 + 16 + colid] = f2b(e[1]*inv);
        gpk[mt][rr] = (u32)f2b(e[2]*inv) | ((u32)f2b(e[3]*inv) << 16);
      }
    floatx4 o[4][2];
    #pragma unroll
    for(int mt=0;mt<4;++mt){ o[mt][0]=fzero; o[mt][1]=fzero; }
    #pragma unroll
    for(int kc=0;kc<2;++kc){
      if(kc==1){
        #pragma unroll
        for(int mt=0;mt<4;++mt)
          #pragma unroll
          for(int rr=0;rr<4;++rr){
            int row = mt*16 + quad*4 + rr;
            sc[row*36 + colid]      = (u16)(gpk[mt][rr] & 0xffffu);
            sc[row*36 + 16 + colid] = (u16)(gpk[mt][rr] >> 16);
          }
      }
      short8 ap[4];
      #pragma unroll
      for(int mt=0;mt<4;++mt) ap[mt] = *(const short8*)&sc[(mt*16+colid)*36 + quad*8];
      #pragma unroll
      for(int mt=0;mt<4;++mt)
        #pragma unroll
        for(int n2=0;n2<2;++n2) o[mt][n2] = MFMA16(ap[mt], bv2[hi][n2][kc], o[mt][n2]);
    }
    // y into XW (wave-own columns)
    #pragma unroll
    for(int n2=0;n2<2;++n2){
      int c = h*32 + n2*16 + colid;
      #pragma unroll
      for(int mt=0;mt<4;++mt)
        #pragma unroll
        for(int rr=0;rr<4;++rr)
          lds[(mt*16+quad*4+rr)*264 + c] = f2b(o[mt][n2][rr]);
    }
  }
  __syncthreads();   // y complete

  // ---- Dump y -> workspace, coalesced 512B rows at the un-shifted image column ----
  const size_t bandbase = (size_t)r0 * (512*256);
  #pragma unroll
  for(int i=0;i<8;++i){
    int unit = i*256 + tid;            // 2048 16B-units (64 tok x 32 chunks)
    int tokw = unit>>5, c8 = unit&31;
    int tyw = tokw>>3, txw = tokw&7;
    int cg = (8*wx + 4 + txw) & 63;    // un-shifted image column
    size_t t = (size_t)(tyw*64 + cg);
    *(short8*)&yws[bandbase + t*256 + c8*8] = *(const short8*)&lds[tokw*264 + c8*8];
  }
}

// ================= Kernel B: out = y @ w_o + b_o, full-line stores =================
// grid 2048: block = (band 256) x (h2 2) x (npp 4); owns 4 rows x 64 cols x 64 ch.
__global__ __launch_bounds__(256,3) void swmsa_proj(
    const u16* __restrict__ yws, const u16* __restrict__ woT,
    const float* __restrict__ bo, float* __restrict__ out)
{
  __shared__ u16 tile[2][256*32];      // 32 KB double-buffered A-tile [256 tok][32 k]
  const int tid = threadIdx.x;
  const int wave = tid>>6, lane = tid&63;
  const int quad = lane>>4, colid = lane&15;
  // XCD swizzle: the 8 sub-blocks (h2 x npp) of a band run on one XCD (share y in L2)
  const int bi = blockIdx.x;
  const int x7 = bi&7, jj = bi>>3;
  const int band = ((jj>>3)<<3) | x7;          // 0..255
  const int sub = jj&7, h2 = sub>>2, npp = sub&3;
  const int b = band>>3, wy = band&7;
  const u16* ybase = yws + (size_t)band*(512*256) + (size_t)h2*(256*256);
  const int ch = npp*64 + wave*16 + colid;
  const u16* wbase = woT + (size_t)ch*256 + quad*8;
  const floatx4 fzero = {0.f,0.f,0.f,0.f};
  floatx4 acc[16];
  #pragma unroll
  for(int mt=0;mt<16;++mt) acc[mt]=fzero;

  const int rbase0 = tid>>2, slot = tid&3;     // thread -> (row r = i*64+rbase0, 16B slot)
  const int swz = (tid>>3)&3;                  // = ((r>>1)&3), row bits
  const int rsw = (colid>>1)&3;                // read-side swizzle for row mt*16+colid

  // prologue: stage k-chunk 0
  short8 sv[4];
  #pragma unroll
  for(int i=0;i<4;++i)
    sv[i] = *(const short8*)&ybase[(size_t)(i*64 + rbase0)*256 + slot*8];
  #pragma unroll
  for(int i=0;i<4;++i)
    *(short8*)&tile[0][(i*64+rbase0)*32 + ((slot^swz))*8] = sv[i];
  __syncthreads();

  for(int kk=0;kk<8;++kk){
    const int cur = kk&1;
    if(kk<7){
      #pragma unroll
      for(int i=0;i<4;++i)
        sv[i] = *(const short8*)&ybase[(size_t)(i*64 + rbase0)*256 + (kk+1)*32 + slot*8];
    }
    short8 bw = *(const short8*)&wbase[kk*32];
    #pragma unroll
    for(int mt=0;mt<16;++mt){
      short8 a = *(const short8*)&tile[cur][(mt*16+colid)*32 + ((quad^rsw))*8];
      acc[mt] = MFMA16(a, bw, acc[mt]);
    }
    if(kk<7){
      #pragma unroll
      for(int i=0;i<4;++i)
        *(short8*)&tile[cur^1][(i*64+rbase0)*32 + ((slot^swz))*8] = sv[i];
    }
    __syncthreads();
  }

  const float bias = bo[ch];
  float* obase = out + (size_t)b*256*4096 + (size_t)ch*4096;
  #pragma unroll
  for(int mt=0;mt<16;++mt){
    int ty = mt>>2;                            // band row 0..3
    int hd = (wy*8 + h2*4 + ty + 4) & 63;      // un-shifted image row
    int colb = (mt&3)*16 + quad*4;             // 16B-aligned 4-col chunk
    floatx4 v = acc[mt];
    v[0]+=bias; v[1]+=bias; v[2]+=bias; v[3]+=bias;
    *(floatx4*)(obase + (size_t)hd*64 + colb) = v;
  }
}

// ================= Fallback: round-1 fused kernel (if workspace too small) =================
__global__ __launch_bounds__(256,3) void swmsa_fused(
    const float* __restrict__ x, const u16* __restrict__ wqkvT, const float* __restrict__ bqkv,
    const u16* __restrict__ woT, const float* __restrict__ bo, const float* __restrict__ table,
    float* __restrict__ out)
{
  extern __shared__ u16 lds[];
  const int tid  = threadIdx.x;
  const int wave = tid>>6, lane = tid&63;
  const int quad = lane>>4, colid = lane&15;
  const int bi = blockIdx.x;
  const int xcd = bi & 7, j = bi >> 3;
  const int r0 = ((j >> 3) << 3) | xcd;
  const int wx = j & 7;
  const int b = r0 >> 3, wy = r0 & 7;
  const size_t imgbase = (size_t)b*256*4096;
  const int w0 = wx*8+4;
  const floatx4 fzero = {0.f,0.f,0.f,0.f};
  u16* sc = lds + SCO + wave*2304;

  for(int i=0;i<2;++i){
    int unit = tid + 256*i;
    int cg = unit>>3, ty = unit&7;
    int hs = (wy*8+ty+4)&63;
    u16 vv[4][8];
    #pragma unroll
    for(int cc=0;cc<4;++cc){
      const float* src = x + imgbase + (size_t)(cg*4+cc)*4096 + (size_t)hs*64;
      floatx4 lo, hi;
      if(wx<7){ lo = *(const floatx4*)(src+w0); hi = *(const floatx4*)(src+w0+4); }
      else    { lo = *(const floatx4*)(src+60); hi = *(const floatx4*)(src); }
      #pragma unroll
      for(int t=0;t<4;++t){ vv[cc][t]=f2b(lo[t]); vv[cc][4+t]=f2b(hi[t]); }
    }
    #pragma unroll
    for(int t=0;t<8;++t){
      uint64_t pk = (uint64_t)vv[0][t] | ((uint64_t)vv[1][t]<<16)
                  | ((uint64_t)vv[2][t]<<32) | ((uint64_t)vv[3][t]<<48);
      *(uint64_t*)&lds[(ty*8+t)*264 + cg*4] = pk;
    }
  }
  __syncthreads();

  short8 aq2[2][4], bk2[2][4], bv2[2][2][2];
  for(int t3=0; t3<3; ++t3){
    const int cc = 2 - t3;
    const int col0 = (cc*4 + wave)*64;
    const u16* wslab = wqkvT + (size_t)(col0+colid)*256 + quad*8;
    floatx4 acc[4][4];
    #pragma unroll
    for(int mt=0;mt<4;++mt)
      #pragma unroll
      for(int nt=0;nt<4;++nt) acc[mt][nt] = fzero;
    short8 bcur[4], bnxt[4];
    #pragma unroll
    for(int nt=0;nt<4;++nt) bcur[nt] = *(const short8*)&wslab[(size_t)nt*16*256];
    for(int k0=0;k0<256;k0+=32){
      short8 af[4];
      #pragma unroll
      for(int mt=0;mt<4;++mt) af[mt]  = *(const short8*)&lds[(mt*16+colid)*264 + k0 + quad*8];
      if(k0 < 224){
        #pragma unroll
        for(int nt=0;nt<4;++nt) bnxt[nt] = *(const short8*)&wslab[(size_t)nt*16*256 + k0 + 32];
      }
      #pragma unroll
      for(int mt=0;mt<4;++mt)
        #pragma unroll
        for(int nt=0;nt<4;++nt) acc[mt][nt] = MFMA16(af[mt], bcur[nt], acc[mt][nt]);
      #pragma unroll
      for(int nt=0;nt<4;++nt) bcur[nt] = bnxt[nt];
    }
    #pragma unroll
    for(int hf=0; hf<2; ++hf){
      #pragma unroll
      for(int nt2=0; nt2<2; ++nt2){
        int nt = hf*2 + nt2;
        float bias = bqkv[col0 + nt*16 + colid];
        #pragma unroll
        for(int mt=0;mt<4;++mt)
          #pragma unroll
          for(int rr=0;rr<4;++rr){
            int row = mt*16 + quad*4 + rr;
            u16 bvv = f2b(acc[mt][nt][rr] + bias);
            if(cc==2) sc[(nt2*16+colid)*72 + row] = bvv;
            else      sc[row*36 + nt2*16 + colid] = bvv;
          }
      }
      if(cc==2){
        #pragma unroll
        for(int n2=0;n2<2;++n2)
          #pragma unroll
          for(int kc=0;kc<2;++kc)
            bv2[hf][n2][kc] = *(const short8*)&sc[(n2*16+colid)*72 + kc*32 + quad*8];
      } else if(cc==1){
        #pragma unroll
        for(int mt=0;mt<4;++mt) bk2[hf][mt] = *(const short8*)&sc[(mt*16+colid)*36 + quad*8];
      } else {
        #pragma unroll
        for(int mt=0;mt<4;++mt) aq2[hf][mt] = *(const short8*)&sc[(mt*16+colid)*36 + quad*8];
      }
    }
  }
  __syncthreads();

  const float scale = 0.17677669529663687f;
  #pragma unroll
  for(int hi=0; hi<2; ++hi){
    const int h = wave*2 + hi;
    floatx4 s[4][4];
    #pragma unroll
    for(int mt=0;mt<4;++mt)
      #pragma unroll
      for(int nt=0;nt<4;++nt) s[mt][nt] = MFMA16(aq2[hi][mt], bk2[hi][nt], fzero);
    int cntk[4], kys[4], kxs[4];
    #pragma unroll
    for(int nt=0;nt<4;++nt){
      int col = nt*16 + colid;
      kys[nt] = col>>3; kxs[nt] = col&7;
      cntk[nt] = regid(wy*8 + kys[nt])*3 + regid(wx*8 + kxs[nt]);
    }
    #pragma unroll
    for(int mt=0;mt<4;++mt)
      #pragma unroll
      for(int rr=0;rr<4;++rr){
        int row = mt*16 + quad*4 + rr;
        int ty = row>>3, tx = row&7;
        int cntq = regid(wy*8+ty)*3 + regid(wx*8+tx);
        #pragma unroll
        for(int nt=0;nt<4;++nt){
          int rel = (ty - kys[nt] + 7)*15 + (tx - kxs[nt] + 7);
          float add = table[rel*8 + h] + ((cntq==cntk[nt]) ? 0.f : -100.f);
          s[mt][nt][rr] = s[mt][nt][rr]*scale + add;
        }
      }
    u32 gpk[4][4];
    #pragma unroll
    for(int mt=0;mt<4;++mt)
      #pragma unroll
      for(int rr=0;rr<4;++rr){
        float mx = s[mt][0][rr];
        #pragma unroll
        for(int nt=1;nt<4;++nt) mx = fmaxf(mx, s[mt][nt][rr]);
        #pragma unroll
        for(int d=1; d<16; d<<=1) mx = fmaxf(mx, __shfl_xor(mx, d));
        float e[4], sum = 0.f;
        #pragma unroll
        for(int nt=0;nt<4;++nt){ e[nt] = __expf(s[mt][nt][rr]-mx); sum += e[nt]; }
        #pragma unroll
        for(int d=1; d<16; d<<=1) sum += __shfl_xor(sum, d);
        float inv = 1.0f/sum;
        int row = mt*16 + quad*4 + rr;
        sc[row*36 + colid]      = f2b(e[0]*inv);
        sc[row*36 + 16 + colid] = f2b(e[1]*inv);
        gpk[mt][rr] = (u32)f2b(e[2]*inv) | ((u32)f2b(e[3]*inv) << 16);
      }
    floatx4 o[4][2];
    #pragma unroll
    for(int mt=0;mt<4;++mt){ o[mt][0]=fzero; o[mt][1]=fzero; }
    #pragma unroll
    for(int kc=0;kc<2;++kc){
      if(kc==1){
        #pragma unroll
        for(int mt=0;mt<4;++mt)
          #pragma unroll
          for(int rr=0;rr<4;++rr){
            int row = mt*16 + quad*4 + rr;
            sc[row*36 + colid]      = (u16)(gpk[mt][rr] & 0xffffu);
            sc[row*36 + 16 + colid] = (u16)(gpk[mt][rr] >> 16);
          }
      }
      short8 ap[4];
      #pragma unroll
      for(int mt=0;mt<4;++mt) ap[mt] = *(const short8*)&sc[(mt*16+colid)*36 + quad*8];
      #pragma unroll
      for(int mt=0;mt<4;++mt)
        #pragma unroll
        for(int n2=0;n2<2;++n2) o[mt][n2] = MFMA16(ap[mt], bv2[hi][n2][kc], o[mt][n2]);
    }
    #pragma unroll
    for(int n2=0;n2<2;++n2){
      int c = h*32 + n2*16 + colid;
      #pragma unroll
      for(int mt=0;mt<4;++mt)
        #pragma unroll
        for(int rr=0;rr<4;++rr)
          lds[(mt*16+quad*4+rr)*264 + c] = f2b(o[mt][n2][rr]);
    }
  }
  __syncthreads();

  {
    floatx4 acc[4][4];
    #pragma unroll
    for(int np=0;np<4;++np)
      #pragma unroll
      for(int mt=0;mt<4;++mt) acc[np][mt] = fzero;
    const u16* wbase = woT + (size_t)(wave*16+colid)*256 + quad*8;
    for(int k0=0;k0<256;k0+=32){
      short8 ay[4];
      #pragma unroll
      for(int mt=0;mt<4;++mt) ay[mt] = *(const short8*)&lds[(mt*16+colid)*264 + k0 + quad*8];
      #pragma unroll
      for(int np=0;np<4;++np){
        short8 bw = *(const short8*)&wbase[(size_t)np*16384 + k0];
        #pragma unroll
        for(int mt=0;mt<4;++mt) acc[np][mt] = MFMA16(ay[mt], bw, acc[np][mt]);
      }
    }
    const int ty_base = quad>>1, txg = quad&1;
    const int col = (wx<7) ? (w0 + 4*txg) : (txg ? 0 : 60);
    #pragma unroll
    for(int np=0;np<4;++np){
      const int ch = np*64 + wave*16 + colid;
      const float bias = bo[ch];
      float* chbase = out + imgbase + (size_t)ch*4096;
      #pragma unroll
      for(int mt=0;mt<4;++mt){
        int ty = 2*mt + ty_base;
        int hd = (wy*8 + ty + 4)&63;
        floatx4 vsto = acc[np][mt];
        vsto[0]+=bias; vsto[1]+=bias; vsto[2]+=bias; vsto[3]+=bias;
        *(floatx4*)(chbase + (size_t)hd*64 + col) = vsto;
      }
    }
  }
}

extern "C" void kernel_launch(void* const* d_in, const int* in_sizes, int n_in,
                              void* d_out, int out_size, void* d_ws, size_t ws_size,
                              hipStream_t stream) {
  const float* x     = (const float*)d_in[0];
  const float* wqkv  = (const float*)d_in[1];
  const float* bqkv  = (const float*)d_in[2];
  const float* wo    = (const float*)d_in[3];
  const float* bo    = (const float*)d_in[4];
  const float* table = (const float*)d_in[5];
  float* out = (float*)d_out;

  u16* wqkvT = (u16*)d_ws;            // 768x256 bf16
  u16* woT   = wqkvT + 768*256;       // 256x256 bf16
  u16* yws   = woT   + 256*256;       // 256 bands x 512 tok x 256 ch bf16 = 67.1 MB

  const size_t need = (size_t)(768*256 + 256*256)*2 + (size_t)256*512*256*2;

  prep_w<<<1024, 256, 0, stream>>>(wqkv, wo, wqkvT, woT);

  if(ws_size >= need){
    (void)hipFuncSetAttribute((const void*)swmsa_attn,
                              hipFuncAttributeMaxDynamicSharedMemorySize, LDS_ELEMS*2);
    swmsa_attn<<<2048, 256, LDS_ELEMS*2, stream>>>(x, wqkvT, bqkv, table, yws);
    swmsa_proj<<<2048, 256, 0, stream>>>(yws, woT, bo, out);
  } else {
    (void)hipFuncSetAttribute((const void*)swmsa_fused,
                              hipFuncAttributeMaxDynamicSharedMemorySize, LDS_ELEMS*2);
    swmsa_fused<<<2048, 256, LDS_ELEMS*2, stream>>>(x, wqkvT, bqkv, woT, bo, table, out);
  }
}